// Round 1
// 826.872 us; speedup vs baseline: 1.1513x; 1.1513x over previous
//
#include <hip/hip_runtime.h>
#include <hip/hip_fp16.h>

#define NN 100000
#define NE 1600000
#define FD 128
#define OS 512   // output row stride: [feat | h1 | h2 | h3]
#define LDA 136  // LDS row stride in bf16 elems (128 + 8 pad -> bank-conflict-free)

typedef __attribute__((ext_vector_type(8))) short short8;
typedef __attribute__((ext_vector_type(4))) float f32x4;

__device__ __forceinline__ short f2bf(float x) {
    unsigned u = __float_as_uint(x);
    u = (u + 0x7fff + ((u >> 16) & 1)) >> 16;   // round-to-nearest-even
    return (short)u;
}

// ---------------- init: copy feat into cols 0:128 of out ----------------
__global__ void k_init_out(const float* __restrict__ feat, float* __restrict__ out) {
    const size_t total = (size_t)NN * 32;  // float4s per feat row
    for (size_t i = (size_t)blockIdx.x * blockDim.x + threadIdx.x; i < total;
         i += (size_t)gridDim.x * blockDim.x) {
        size_t n = i >> 5;
        int c4 = (int)(i & 31);
        ((float4*)(out + n * OS))[c4] = ((const float4*)feat)[n * 32 + c4];
    }
}

// ---------------- prep: Wt[l][n][k] = bf16(W_l[k][n]) ----------------
__global__ void k_prep_w(const float* __restrict__ W0, const float* __restrict__ W1,
                         const float* __restrict__ W2, short* __restrict__ Wt) {
    int i = blockIdx.x * blockDim.x + threadIdx.x;
    if (i >= 3 * FD * FD) return;
    int l = i >> 14, r = i & (FD * FD - 1);
    int n = r >> 7, k = r & 127;
    const float* W = (l == 0) ? W0 : ((l == 1) ? W1 : W2);
    Wt[i] = f2bf(W[k * FD + n]);   // i = l*16384 + n*128 + k
}

// ---------------- degree histogram (int atomics, int4 edge loads) ----------------
__global__ void k_degrees(const int* __restrict__ src, const int* __restrict__ dst,
                          int* __restrict__ cnt_out, int* __restrict__ cnt_in) {
    const int total4 = NE / 4;
    for (int i = blockIdx.x * blockDim.x + threadIdx.x; i < total4;
         i += gridDim.x * blockDim.x) {
        int4 s = ((const int4*)src)[i];
        int4 d = ((const int4*)dst)[i];
        atomicAdd(&cnt_out[s.x], 1); atomicAdd(&cnt_out[s.y], 1);
        atomicAdd(&cnt_out[s.z], 1); atomicAdd(&cnt_out[s.w], 1);
        atomicAdd(&cnt_in[d.x], 1); atomicAdd(&cnt_in[d.y], 1);
        atomicAdd(&cnt_in[d.z], 1); atomicAdd(&cnt_in[d.w], 1);
    }
}

__global__ void k_invsqrt(const int* __restrict__ cnt, float* __restrict__ inv, int n) {
    int i = blockIdx.x * blockDim.x + threadIdx.x;
    if (i < n) inv[i] = rsqrtf((float)max(cnt[i], 1));
}

// ---------------- single-block scan, 4 elems/thread ----------------
__global__ __launch_bounds__(1024) void k_scan(const int* __restrict__ cnt_in,
                                               int* __restrict__ row_ptr,
                                               int* __restrict__ cursor) {
    __shared__ int wsum[16];
    __shared__ int wscan[16];
    __shared__ int carry_s;
    const int tid = threadIdx.x;
    const int lane = tid & 63;
    const int wid = tid >> 6;
    if (tid == 0) carry_s = 0;
    __syncthreads();
    for (int base = 0; base < NN; base += 4096) {
        const int i0 = base + tid * 4;
        int4 v = make_int4(0, 0, 0, 0);
        if (i0 + 3 < NN) {
            v = ((const int4*)(cnt_in + base))[tid];
        } else {
            if (i0 < NN) v.x = cnt_in[i0];
            if (i0 + 1 < NN) v.y = cnt_in[i0 + 1];
            if (i0 + 2 < NN) v.z = cnt_in[i0 + 2];
            if (i0 + 3 < NN) v.w = cnt_in[i0 + 3];
        }
        const int s = v.x + v.y + v.z + v.w;
        int incl = s;
        #pragma unroll
        for (int off = 1; off < 64; off <<= 1) {
            int t = __shfl_up(incl, off, 64);
            if (lane >= off) incl += t;
        }
        if (lane == 63) wsum[wid] = incl;
        __syncthreads();
        if (wid == 0) {
            int t = (lane < 16) ? wsum[lane] : 0;
            #pragma unroll
            for (int off = 1; off < 16; off <<= 1) {
                int u = __shfl_up(t, off, 64);
                if (lane >= off) t += u;
            }
            if (lane < 16) wscan[lane] = t;
        }
        __syncthreads();
        const int wbase = (wid > 0) ? wscan[wid - 1] : 0;
        int p = carry_s + wbase + incl - s;
        if (i0 < NN) { row_ptr[i0] = p; cursor[i0] = p; }
        if (i0 + 1 < NN) { row_ptr[i0 + 1] = p + v.x; cursor[i0 + 1] = p + v.x; }
        if (i0 + 2 < NN) { row_ptr[i0 + 2] = p + v.x + v.y; cursor[i0 + 2] = p + v.x + v.y; }
        if (i0 + 3 < NN) { row_ptr[i0 + 3] = p + v.x + v.y + v.z; cursor[i0 + 3] = p + v.x + v.y + v.z; }
        __syncthreads();
        if (tid == 0) carry_s += wscan[15];
        __syncthreads();
    }
    if (tid == 0) row_ptr[NN] = carry_s;
}

// ---------------- CSR fill: counting sort edges by dst ----------------
__global__ void k_csr_fill(const int* __restrict__ src, const int* __restrict__ dst,
                           int* __restrict__ cursor, int* __restrict__ col) {
    for (int e = blockIdx.x * blockDim.x + threadIdx.x; e < NE;
         e += gridDim.x * blockDim.x) {
        int pos = atomicAdd(&cursor[dst[e]], 1);
        col[pos] = src[e];
    }
}

// ---------------- MFMA GEMM: tmp[r][:] = fp16(inv_out[r] * (bf16(h[r][:]) @ bf16(W)))
// block = 256 thr (4 waves); 128-row tile, 2 sub-iters of 64 rows; wave owns 16 rows.
__global__ __launch_bounds__(256) void k_gemm(const float* __restrict__ h, int hstride,
                                              const short* __restrict__ Wt,
                                              const float* __restrict__ inv_out,
                                              __half* __restrict__ tmp) {
    __shared__ short Ws[FD * LDA];   // Wt[n][k], padded rows: 34 KB
    __shared__ short hA[64 * LDA];   // h tile bf16, padded rows: 17 KB
    const int tid = threadIdx.x;
    // stage Wt (coalesced 16B chunks), bank-friendly padded rows
    for (int i = tid; i < FD * 16; i += 256) {   // 2048 chunks of 8 bf16
        int n = i >> 4, c = i & 15;
        short8 v = *(const short8*)(Wt + n * FD + c * 8);
        *(short8*)(&Ws[n * LDA + c * 8]) = v;
    }
    const int row0 = blockIdx.x * 128;
    const int wid = tid >> 6, lane = tid & 63;
    const int m = lane & 15, quad = lane >> 4;

    for (int sub = 0; sub < 2; ++sub) {
        const int rbase = row0 + sub * 64;
        __syncthreads();   // sub0: Ws staged; sub>0: prev compute done before hA overwrite
        // stage 64 rows of h -> bf16 in hA
        for (int i = tid; i < 64 * 32; i += 256) {   // float4 chunks
            int r = i >> 5, c4 = i & 31;
            int gr = rbase + r;
            float4 v = make_float4(0.f, 0.f, 0.f, 0.f);
            if (gr < NN) v = ((const float4*)(h + (size_t)gr * hstride))[c4];
            short4 b;
            b.x = f2bf(v.x); b.y = f2bf(v.y); b.z = f2bf(v.z); b.w = f2bf(v.w);
            *(short4*)(&hA[r * LDA + c4 * 4]) = b;
        }
        __syncthreads();
        const int rtile = rbase + wid * 16;          // this wave's 16 rows
        // A fragments: reused across all 8 col-tiles
        short8 a0 = *(const short8*)(&hA[(wid * 16 + m) * LDA + 0 * 32 + quad * 8]);
        short8 a1 = *(const short8*)(&hA[(wid * 16 + m) * LDA + 1 * 32 + quad * 8]);
        short8 a2 = *(const short8*)(&hA[(wid * 16 + m) * LDA + 2 * 32 + quad * 8]);
        short8 a3 = *(const short8*)(&hA[(wid * 16 + m) * LDA + 3 * 32 + quad * 8]);
        // row scales for this lane's 4 output rows
        float s0, s1, s2, s3;
        {
            int r = rtile + quad * 4;
            s0 = (r + 0 < NN) ? inv_out[r + 0] : 0.f;
            s1 = (r + 1 < NN) ? inv_out[r + 1] : 0.f;
            s2 = (r + 2 < NN) ? inv_out[r + 2] : 0.f;
            s3 = (r + 3 < NN) ? inv_out[r + 3] : 0.f;
        }
        #pragma unroll
        for (int ct = 0; ct < 8; ++ct) {
            f32x4 acc = {0.f, 0.f, 0.f, 0.f};
            short8 b0 = *(const short8*)(&Ws[(ct * 16 + m) * LDA + 0 * 32 + quad * 8]);
            short8 b1 = *(const short8*)(&Ws[(ct * 16 + m) * LDA + 1 * 32 + quad * 8]);
            short8 b2 = *(const short8*)(&Ws[(ct * 16 + m) * LDA + 2 * 32 + quad * 8]);
            short8 b3 = *(const short8*)(&Ws[(ct * 16 + m) * LDA + 3 * 32 + quad * 8]);
            acc = __builtin_amdgcn_mfma_f32_16x16x32_bf16(a0, b0, acc, 0, 0, 0);
            acc = __builtin_amdgcn_mfma_f32_16x16x32_bf16(a1, b1, acc, 0, 0, 0);
            acc = __builtin_amdgcn_mfma_f32_16x16x32_bf16(a2, b2, acc, 0, 0, 0);
            acc = __builtin_amdgcn_mfma_f32_16x16x32_bf16(a3, b3, acc, 0, 0, 0);
            // D: col = ct*16 + m, rows = rtile + quad*4 + reg
            const int r = rtile + quad * 4;
            const int c = ct * 16 + m;
            if (r + 3 < NN) {
                tmp[(size_t)(r + 0) * FD + c] = __float2half_rn(acc[0] * s0);
                tmp[(size_t)(r + 1) * FD + c] = __float2half_rn(acc[1] * s1);
                tmp[(size_t)(r + 2) * FD + c] = __float2half_rn(acc[2] * s2);
                tmp[(size_t)(r + 3) * FD + c] = __float2half_rn(acc[3] * s3);
            } else {
                if (r + 0 < NN) tmp[(size_t)(r + 0) * FD + c] = __float2half_rn(acc[0] * s0);
                if (r + 1 < NN) tmp[(size_t)(r + 1) * FD + c] = __float2half_rn(acc[1] * s1);
                if (r + 2 < NN) tmp[(size_t)(r + 2) * FD + c] = __float2half_rn(acc[2] * s2);
                if (r + 3 < NN) tmp[(size_t)(r + 3) * FD + c] = __float2half_rn(acc[3] * s3);
            }
        }
    }
}

// ---------------- gather: out[d][off:off+128] = relu(inv_in[d]*sum tmp[s] + b) ----
// tmp rows are fp16 (256 B); one wave per node, one __half2 (4 B) per lane per edge.
__global__ __launch_bounds__(256) void k_gather(const __half* __restrict__ tmp,
                                                const int* __restrict__ row_ptr,
                                                const int* __restrict__ col,
                                                const float* __restrict__ inv_in,
                                                const float* __restrict__ b,
                                                float* __restrict__ out, int off) {
    const int wid = threadIdx.x >> 6;
    const int lane = threadIdx.x & 63;
    const int node = blockIdx.x * 4 + wid;
    if (node >= NN) return;
    const int beg = row_ptr[node], end = row_ptr[node + 1];
    const __half2* t2 = (const __half2*)tmp;
    float2 acc = make_float2(0.f, 0.f);
    int j = beg;
    for (; j + 3 < end; j += 4) {
        int s0 = col[j], s1 = col[j + 1], s2 = col[j + 2], s3 = col[j + 3];
        __half2 v0 = t2[(size_t)s0 * 64 + lane];
        __half2 v1 = t2[(size_t)s1 * 64 + lane];
        __half2 v2 = t2[(size_t)s2 * 64 + lane];
        __half2 v3 = t2[(size_t)s3 * 64 + lane];
        float2 f0 = __half22float2(v0);
        float2 f1 = __half22float2(v1);
        float2 f2 = __half22float2(v2);
        float2 f3 = __half22float2(v3);
        acc.x += (f0.x + f1.x) + (f2.x + f3.x);
        acc.y += (f0.y + f1.y) + (f2.y + f3.y);
    }
    for (; j < end; ++j) {
        int s0 = col[j];
        float2 f0 = __half22float2(t2[(size_t)s0 * 64 + lane]);
        acc.x += f0.x;
        acc.y += f0.y;
    }
    const float s = inv_in[node];
    const float2 bb = ((const float2*)b)[lane];
    float2 r;
    r.x = fmaxf(acc.x * s + bb.x, 0.f);
    r.y = fmaxf(acc.y * s + bb.y, 0.f);
    ((float2*)(out + (size_t)node * OS + off))[lane] = r;
}

extern "C" void kernel_launch(void* const* d_in, const int* in_sizes, int n_in,
                              void* d_out, int out_size, void* d_ws, size_t ws_size,
                              hipStream_t stream) {
    const float* feat = (const float*)d_in[0];
    const float* W0 = (const float*)d_in[1];
    const float* b0 = (const float*)d_in[2];
    const float* W1 = (const float*)d_in[3];
    const float* b1 = (const float*)d_in[4];
    const float* W2 = (const float*)d_in[5];
    const float* b2 = (const float*)d_in[6];
    const int* src = (const int*)d_in[7];
    const int* dst = (const int*)d_in[8];
    float* out = (float*)d_out;
    float* ws = (float*)d_ws;

    __half* tmp = (__half*)ws;                // NN*FD halves (region sized as NN*FD floats)
    int* cnt = (int*)(ws + (size_t)NN * FD);  // 2N ints (cnt_out | cnt_in)
    float* inv = (float*)(cnt + 2 * NN);      // 2N floats (inv_out | inv_in)
    int* row_ptr = (int*)(inv + 2 * NN);      // N+1 ints
    int* cursor = row_ptr + NN + 1;           // N ints
    int* col = cursor + NN;                   // NE ints
    short* Wt = (short*)(col + NE);           // 3*FD*FD bf16

    hipMemsetAsync(cnt, 0, 2 * NN * sizeof(int), stream);
    k_init_out<<<4096, 256, 0, stream>>>(feat, out);
    k_prep_w<<<(3 * FD * FD + 255) / 256, 256, 0, stream>>>(W0, W1, W2, Wt);
    k_degrees<<<2048, 256, 0, stream>>>(src, dst, cnt, cnt + NN);
    k_invsqrt<<<(2 * NN + 255) / 256, 256, 0, stream>>>(cnt, inv, 2 * NN);
    k_scan<<<1, 1024, 0, stream>>>(cnt + NN, row_ptr, cursor);
    k_csr_fill<<<4096, 256, 0, stream>>>(src, dst, cursor, col);

    const float* bs[3] = {b0, b1, b2};
    const float* h = feat;
    int hstride = FD;
    for (int l = 0; l < 3; ++l) {
        k_gemm<<<(NN + 127) / 128, 256, 0, stream>>>(h, hstride, Wt + l * FD * FD, inv, tmp);
        k_gather<<<(NN + 3) / 4, 256, 0, stream>>>(tmp, row_ptr, col, inv + NN, bs[l], out,
                                                   FD * (l + 1));
        h = out + FD * (l + 1);
        hstride = OS;
    }
}

// Round 2
// 775.080 us; speedup vs baseline: 1.2282x; 1.0668x over previous
//
#include <hip/hip_runtime.h>
#include <hip/hip_fp16.h>

#define NN 100000
#define NE 1600000
#define FD 128
#define OS 512   // output row stride: [feat | h1 | h2 | h3]
#define LDA 136  // LDS row stride in bf16 elems (128 + 8 pad -> bank-conflict-free)
#define NBKT 196 // dst buckets of 512 nodes: (99999>>9)=195 -> 196 buckets
#define PCH 4096 // edges per block in partition pass

typedef __attribute__((ext_vector_type(8))) short short8;
typedef __attribute__((ext_vector_type(4))) float f32x4;

__device__ __forceinline__ short f2bf(float x) {
    unsigned u = __float_as_uint(x);
    u = (u + 0x7fff + ((u >> 16) & 1)) >> 16;   // round-to-nearest-even
    return (short)u;
}

// ---------------- init: copy feat into cols 0:128 of out ----------------
__global__ void k_init_out(const float* __restrict__ feat, float* __restrict__ out) {
    const size_t total = (size_t)NN * 32;  // float4s per feat row
    for (size_t i = (size_t)blockIdx.x * blockDim.x + threadIdx.x; i < total;
         i += (size_t)gridDim.x * blockDim.x) {
        size_t n = i >> 5;
        int c4 = (int)(i & 31);
        ((float4*)(out + n * OS))[c4] = ((const float4*)feat)[n * 32 + c4];
    }
}

// ---------------- prep: Wt[l][n][k] = bf16(W_l[k][n]) ----------------
__global__ void k_prep_w(const float* __restrict__ W0, const float* __restrict__ W1,
                         const float* __restrict__ W2, short* __restrict__ Wt) {
    int i = blockIdx.x * blockDim.x + threadIdx.x;
    if (i >= 3 * FD * FD) return;
    int l = i >> 14, r = i & (FD * FD - 1);
    int n = r >> 7, k = r & 127;
    const float* W = (l == 0) ? W0 : ((l == 1) ? W1 : W2);
    Wt[i] = f2bf(W[k * FD + n]);   // i = l*16384 + n*128 + k
}

// ---------------- degree histogram (int atomics, int4 edge loads) ----------------
__global__ void k_degrees(const int* __restrict__ src, const int* __restrict__ dst,
                          int* __restrict__ cnt_out, int* __restrict__ cnt_in) {
    const int total4 = NE / 4;
    for (int i = blockIdx.x * blockDim.x + threadIdx.x; i < total4;
         i += gridDim.x * blockDim.x) {
        int4 s = ((const int4*)src)[i];
        int4 d = ((const int4*)dst)[i];
        atomicAdd(&cnt_out[s.x], 1); atomicAdd(&cnt_out[s.y], 1);
        atomicAdd(&cnt_out[s.z], 1); atomicAdd(&cnt_out[s.w], 1);
        atomicAdd(&cnt_in[d.x], 1); atomicAdd(&cnt_in[d.y], 1);
        atomicAdd(&cnt_in[d.z], 1); atomicAdd(&cnt_in[d.w], 1);
    }
}

__global__ void k_invsqrt(const int* __restrict__ cnt, float* __restrict__ inv, int n) {
    int i = blockIdx.x * blockDim.x + threadIdx.x;
    if (i < n) inv[i] = rsqrtf((float)max(cnt[i], 1));
}

// ---------------- single-block scan, 4 elems/thread ----------------
__global__ __launch_bounds__(1024) void k_scan(const int* __restrict__ cnt_in,
                                               int* __restrict__ row_ptr,
                                               int* __restrict__ cursor) {
    __shared__ int wsum[16];
    __shared__ int wscan[16];
    __shared__ int carry_s;
    const int tid = threadIdx.x;
    const int lane = tid & 63;
    const int wid = tid >> 6;
    if (tid == 0) carry_s = 0;
    __syncthreads();
    for (int base = 0; base < NN; base += 4096) {
        const int i0 = base + tid * 4;
        int4 v = make_int4(0, 0, 0, 0);
        if (i0 + 3 < NN) {
            v = ((const int4*)(cnt_in + base))[tid];
        } else {
            if (i0 < NN) v.x = cnt_in[i0];
            if (i0 + 1 < NN) v.y = cnt_in[i0 + 1];
            if (i0 + 2 < NN) v.z = cnt_in[i0 + 2];
            if (i0 + 3 < NN) v.w = cnt_in[i0 + 3];
        }
        const int s = v.x + v.y + v.z + v.w;
        int incl = s;
        #pragma unroll
        for (int off = 1; off < 64; off <<= 1) {
            int t = __shfl_up(incl, off, 64);
            if (lane >= off) incl += t;
        }
        if (lane == 63) wsum[wid] = incl;
        __syncthreads();
        if (wid == 0) {
            int t = (lane < 16) ? wsum[lane] : 0;
            #pragma unroll
            for (int off = 1; off < 16; off <<= 1) {
                int u = __shfl_up(t, off, 64);
                if (lane >= off) t += u;
            }
            if (lane < 16) wscan[lane] = t;
        }
        __syncthreads();
        const int wbase = (wid > 0) ? wscan[wid - 1] : 0;
        int p = carry_s + wbase + incl - s;
        if (i0 < NN) { row_ptr[i0] = p; cursor[i0] = p; }
        if (i0 + 1 < NN) { row_ptr[i0 + 1] = p + v.x; cursor[i0 + 1] = p + v.x; }
        if (i0 + 2 < NN) { row_ptr[i0 + 2] = p + v.x + v.y; cursor[i0 + 2] = p + v.x + v.y; }
        if (i0 + 3 < NN) { row_ptr[i0 + 3] = p + v.x + v.y + v.z; cursor[i0 + 3] = p + v.x + v.y + v.z; }
        __syncthreads();
        if (tid == 0) carry_s += wscan[15];
        __syncthreads();
    }
    if (tid == 0) row_ptr[NN] = carry_s;
}

// ---------------- bucket cursors: bkt[b] = row_ptr[b<<9] ----------------
__global__ void k_bkt_init(const int* __restrict__ row_ptr, int* __restrict__ bkt) {
    int b = blockIdx.x * blockDim.x + threadIdx.x;
    if (b < NBKT) bkt[b] = row_ptr[min(b << 9, NN)];
}

// ---------------- P1: radix-partition edges into dst-buckets (pairs) ----------
// Per block: LDS histogram over 196 buckets, reserve global space per bucket,
// then write (src,dst) pairs bucket-contiguously. Writes are dense -> compact
// HBM writeback (vs 16x amplification of the old single-pass random scatter).
__global__ __launch_bounds__(256) void k_part(const int* __restrict__ src,
                                              const int* __restrict__ dst,
                                              int* __restrict__ bkt_cursor,
                                              int2* __restrict__ pairs) {
    __shared__ int hist[NBKT];
    __shared__ int base[NBKT];
    __shared__ int lofs[NBKT];
    const int tid = threadIdx.x;
    const int e0 = blockIdx.x * PCH;
    for (int i = tid; i < NBKT; i += 256) { hist[i] = 0; lofs[i] = 0; }
    __syncthreads();
    int md[16], ms[16];
    #pragma unroll
    for (int k = 0; k < 16; ++k) {
        int e = e0 + k * 256 + tid;
        md[k] = (e < NE) ? dst[e] : -1;
        ms[k] = (e < NE) ? src[e] : 0;
    }
    #pragma unroll
    for (int k = 0; k < 16; ++k)
        if (md[k] >= 0) atomicAdd(&hist[md[k] >> 9], 1);
    __syncthreads();
    for (int i = tid; i < NBKT; i += 256)
        base[i] = hist[i] ? atomicAdd(&bkt_cursor[i], hist[i]) : 0;
    __syncthreads();
    #pragma unroll
    for (int k = 0; k < 16; ++k)
        if (md[k] >= 0) {
            int b = md[k] >> 9;
            int off = atomicAdd(&lofs[b], 1);
            pairs[base[b] + off] = make_int2(ms[k], md[k]);
        }
}

// ---------------- P2: CSR fill from bucket-sorted pairs ----------------
// pairs are dst-bucket-ordered, so each 1024-edge chunk touches a ~4KB col
// window -> compact writebacks. Bijective XCD-chunked swizzle keeps
// consecutive chunks (same bucket region) on the same XCD's L2.
__global__ __launch_bounds__(256) void k_fill2(const int2* __restrict__ pairs,
                                               int* __restrict__ cursor,
                                               int* __restrict__ col, int nblk) {
    // bijective chunked swizzle (m204): consecutive logical chunks -> same XCD
    const int bid = blockIdx.x;
    const int q = nblk >> 3, r = nblk & 7;
    const int xcd = bid & 7, idx = bid >> 3;
    const int logical = (xcd < r ? xcd * (q + 1) : r * (q + 1) + (xcd - r) * q) + idx;
    const int e0 = logical * 1024;
    #pragma unroll
    for (int k = 0; k < 4; ++k) {
        int e = e0 + k * 256 + threadIdx.x;
        if (e < NE) {
            int2 p = pairs[e];
            int pos = atomicAdd(&cursor[p.y], 1);
            col[pos] = p.x;
        }
    }
}

// ---------------- MFMA GEMM: tmp[r][:] = fp16(inv_out[r] * (bf16(h[r][:]) @ bf16(W)))
// block = 256 thr (4 waves); 128-row tile, 2 sub-iters of 64 rows; wave owns 16 rows.
__global__ __launch_bounds__(256) void k_gemm(const float* __restrict__ h, int hstride,
                                              const short* __restrict__ Wt,
                                              const float* __restrict__ inv_out,
                                              __half* __restrict__ tmp) {
    __shared__ short Ws[FD * LDA];   // Wt[n][k], padded rows: 34 KB
    __shared__ short hA[64 * LDA];   // h tile bf16, padded rows: 17 KB
    const int tid = threadIdx.x;
    // stage Wt (coalesced 16B chunks), bank-friendly padded rows
    for (int i = tid; i < FD * 16; i += 256) {   // 2048 chunks of 8 bf16
        int n = i >> 4, c = i & 15;
        short8 v = *(const short8*)(Wt + n * FD + c * 8);
        *(short8*)(&Ws[n * LDA + c * 8]) = v;
    }
    const int row0 = blockIdx.x * 128;
    const int wid = tid >> 6, lane = tid & 63;
    const int m = lane & 15, quad = lane >> 4;

    for (int sub = 0; sub < 2; ++sub) {
        const int rbase = row0 + sub * 64;
        __syncthreads();   // sub0: Ws staged; sub>0: prev compute done before hA overwrite
        // stage 64 rows of h -> bf16 in hA
        for (int i = tid; i < 64 * 32; i += 256) {   // float4 chunks
            int r = i >> 5, c4 = i & 31;
            int gr = rbase + r;
            float4 v = make_float4(0.f, 0.f, 0.f, 0.f);
            if (gr < NN) v = ((const float4*)(h + (size_t)gr * hstride))[c4];
            short4 b;
            b.x = f2bf(v.x); b.y = f2bf(v.y); b.z = f2bf(v.z); b.w = f2bf(v.w);
            *(short4*)(&hA[r * LDA + c4 * 4]) = b;
        }
        __syncthreads();
        const int rtile = rbase + wid * 16;          // this wave's 16 rows
        // A fragments: reused across all 8 col-tiles
        short8 a0 = *(const short8*)(&hA[(wid * 16 + m) * LDA + 0 * 32 + quad * 8]);
        short8 a1 = *(const short8*)(&hA[(wid * 16 + m) * LDA + 1 * 32 + quad * 8]);
        short8 a2 = *(const short8*)(&hA[(wid * 16 + m) * LDA + 2 * 32 + quad * 8]);
        short8 a3 = *(const short8*)(&hA[(wid * 16 + m) * LDA + 3 * 32 + quad * 8]);
        // row scales for this lane's 4 output rows
        float s0, s1, s2, s3;
        {
            int r = rtile + quad * 4;
            s0 = (r + 0 < NN) ? inv_out[r + 0] : 0.f;
            s1 = (r + 1 < NN) ? inv_out[r + 1] : 0.f;
            s2 = (r + 2 < NN) ? inv_out[r + 2] : 0.f;
            s3 = (r + 3 < NN) ? inv_out[r + 3] : 0.f;
        }
        #pragma unroll
        for (int ct = 0; ct < 8; ++ct) {
            f32x4 acc = {0.f, 0.f, 0.f, 0.f};
            short8 b0 = *(const short8*)(&Ws[(ct * 16 + m) * LDA + 0 * 32 + quad * 8]);
            short8 b1 = *(const short8*)(&Ws[(ct * 16 + m) * LDA + 1 * 32 + quad * 8]);
            short8 b2 = *(const short8*)(&Ws[(ct * 16 + m) * LDA + 2 * 32 + quad * 8]);
            short8 b3 = *(const short8*)(&Ws[(ct * 16 + m) * LDA + 3 * 32 + quad * 8]);
            acc = __builtin_amdgcn_mfma_f32_16x16x32_bf16(a0, b0, acc, 0, 0, 0);
            acc = __builtin_amdgcn_mfma_f32_16x16x32_bf16(a1, b1, acc, 0, 0, 0);
            acc = __builtin_amdgcn_mfma_f32_16x16x32_bf16(a2, b2, acc, 0, 0, 0);
            acc = __builtin_amdgcn_mfma_f32_16x16x32_bf16(a3, b3, acc, 0, 0, 0);
            // D: col = ct*16 + m, rows = rtile + quad*4 + reg
            const int r = rtile + quad * 4;
            const int c = ct * 16 + m;
            if (r + 3 < NN) {
                tmp[(size_t)(r + 0) * FD + c] = __float2half_rn(acc[0] * s0);
                tmp[(size_t)(r + 1) * FD + c] = __float2half_rn(acc[1] * s1);
                tmp[(size_t)(r + 2) * FD + c] = __float2half_rn(acc[2] * s2);
                tmp[(size_t)(r + 3) * FD + c] = __float2half_rn(acc[3] * s3);
            } else {
                if (r + 0 < NN) tmp[(size_t)(r + 0) * FD + c] = __float2half_rn(acc[0] * s0);
                if (r + 1 < NN) tmp[(size_t)(r + 1) * FD + c] = __float2half_rn(acc[1] * s1);
                if (r + 2 < NN) tmp[(size_t)(r + 2) * FD + c] = __float2half_rn(acc[2] * s2);
                if (r + 3 < NN) tmp[(size_t)(r + 3) * FD + c] = __float2half_rn(acc[3] * s3);
            }
        }
    }
}

// ---------------- gather: out[d][off:off+128] = relu(inv_in[d]*sum tmp[s] + b) ----
// tmp rows are fp16 (256 B); one wave per node, one __half2 (4 B) per lane per edge.
__global__ __launch_bounds__(256) void k_gather(const __half* __restrict__ tmp,
                                                const int* __restrict__ row_ptr,
                                                const int* __restrict__ col,
                                                const float* __restrict__ inv_in,
                                                const float* __restrict__ b,
                                                float* __restrict__ out, int off) {
    const int wid = threadIdx.x >> 6;
    const int lane = threadIdx.x & 63;
    const int node = blockIdx.x * 4 + wid;
    if (node >= NN) return;
    const int beg = row_ptr[node], end = row_ptr[node + 1];
    const __half2* t2 = (const __half2*)tmp;
    float2 acc = make_float2(0.f, 0.f);
    int j = beg;
    for (; j + 3 < end; j += 4) {
        int s0 = col[j], s1 = col[j + 1], s2 = col[j + 2], s3 = col[j + 3];
        __half2 v0 = t2[(size_t)s0 * 64 + lane];
        __half2 v1 = t2[(size_t)s1 * 64 + lane];
        __half2 v2 = t2[(size_t)s2 * 64 + lane];
        __half2 v3 = t2[(size_t)s3 * 64 + lane];
        float2 f0 = __half22float2(v0);
        float2 f1 = __half22float2(v1);
        float2 f2 = __half22float2(v2);
        float2 f3 = __half22float2(v3);
        acc.x += (f0.x + f1.x) + (f2.x + f3.x);
        acc.y += (f0.y + f1.y) + (f2.y + f3.y);
    }
    for (; j < end; ++j) {
        int s0 = col[j];
        float2 f0 = __half22float2(t2[(size_t)s0 * 64 + lane]);
        acc.x += f0.x;
        acc.y += f0.y;
    }
    const float s = inv_in[node];
    const float2 bb = ((const float2*)b)[lane];
    float2 r;
    r.x = fmaxf(acc.x * s + bb.x, 0.f);
    r.y = fmaxf(acc.y * s + bb.y, 0.f);
    ((float2*)(out + (size_t)node * OS + off))[lane] = r;
}

extern "C" void kernel_launch(void* const* d_in, const int* in_sizes, int n_in,
                              void* d_out, int out_size, void* d_ws, size_t ws_size,
                              hipStream_t stream) {
    const float* feat = (const float*)d_in[0];
    const float* W0 = (const float*)d_in[1];
    const float* b0 = (const float*)d_in[2];
    const float* W1 = (const float*)d_in[3];
    const float* b1 = (const float*)d_in[4];
    const float* W2 = (const float*)d_in[5];
    const float* b2 = (const float*)d_in[6];
    const int* src = (const int*)d_in[7];
    const int* dst = (const int*)d_in[8];
    float* out = (float*)d_out;
    float* ws = (float*)d_ws;

    __half* tmp = (__half*)ws;                // NN*FD halves = 25.6MB of the 51.2MB region
    int2* pairs = (int2*)(ws + (size_t)NN * 64);  // 12.8MB in the free upper half of tmp region
    int* cnt = (int*)(ws + (size_t)NN * FD);  // 2N ints (cnt_out | cnt_in)
    float* inv = (float*)(cnt + 2 * NN);      // 2N floats (inv_out | inv_in)
    int* row_ptr = (int*)(inv + 2 * NN);      // N+1 ints
    int* cursor = row_ptr + NN + 1;           // N ints
    int* col = cursor + NN;                   // NE ints
    short* Wt = (short*)(col + NE);           // 3*FD*FD bf16
    int* bkt = (int*)(Wt + 3 * FD * FD);      // NBKT ints

    hipMemsetAsync(cnt, 0, 2 * NN * sizeof(int), stream);
    k_init_out<<<4096, 256, 0, stream>>>(feat, out);
    k_prep_w<<<(3 * FD * FD + 255) / 256, 256, 0, stream>>>(W0, W1, W2, Wt);
    k_degrees<<<2048, 256, 0, stream>>>(src, dst, cnt, cnt + NN);
    k_invsqrt<<<(2 * NN + 255) / 256, 256, 0, stream>>>(cnt, inv, 2 * NN);
    k_scan<<<1, 1024, 0, stream>>>(cnt + NN, row_ptr, cursor);
    k_bkt_init<<<1, 256, 0, stream>>>(row_ptr, bkt);
    k_part<<<(NE + PCH - 1) / PCH, 256, 0, stream>>>(src, dst, bkt, pairs);
    {
        const int nblk = (NE + 1023) / 1024;
        k_fill2<<<nblk, 256, 0, stream>>>(pairs, cursor, col, nblk);
    }

    const float* bs[3] = {b0, b1, b2};
    const float* h = feat;
    int hstride = FD;
    for (int l = 0; l < 3; ++l) {
        k_gemm<<<(NN + 127) / 128, 256, 0, stream>>>(h, hstride, Wt + l * FD * FD, inv, tmp);
        k_gather<<<(NN + 3) / 4, 256, 0, stream>>>(tmp, row_ptr, col, inv + NN, bs[l], out,
                                                   FD * (l + 1));
        h = out + FD * (l + 1);
        hstride = OS;
    }
}

// Round 3
// 757.331 us; speedup vs baseline: 1.2570x; 1.0234x over previous
//
#include <hip/hip_runtime.h>
#include <hip/hip_fp16.h>

#define NN 100000
#define NE 1600000
#define FD 128
#define OS 512   // output row stride: [feat | h1 | h2 | h3]
#define LDA 136  // LDS row stride in bf16 elems (128 + 8 pad -> bank-conflict-free)
#define NBKT 196 // dst buckets of 512 nodes: (99999>>9)=195 -> 196 buckets
#define PCH 4096 // edges per block in partition pass

typedef __attribute__((ext_vector_type(8))) short short8;
typedef __attribute__((ext_vector_type(4))) float f32x4;

struct h4v { __half2 lo, hi; };   // 8 B = 4 halves

__device__ __forceinline__ short f2bf(float x) {
    unsigned u = __float_as_uint(x);
    u = (u + 0x7fff + ((u >> 16) & 1)) >> 16;   // round-to-nearest-even
    return (short)u;
}

// ---------------- init: copy feat into cols 0:128 of out ----------------
__global__ void k_init_out(const float* __restrict__ feat, float* __restrict__ out) {
    const size_t total = (size_t)NN * 32;  // float4s per feat row
    for (size_t i = (size_t)blockIdx.x * blockDim.x + threadIdx.x; i < total;
         i += (size_t)gridDim.x * blockDim.x) {
        size_t n = i >> 5;
        int c4 = (int)(i & 31);
        ((float4*)(out + n * OS))[c4] = ((const float4*)feat)[n * 32 + c4];
    }
}

// ---------------- prep: Wt[l][n][k] = bf16(W_l[k][n]) ----------------
__global__ void k_prep_w(const float* __restrict__ W0, const float* __restrict__ W1,
                         const float* __restrict__ W2, short* __restrict__ Wt) {
    int i = blockIdx.x * blockDim.x + threadIdx.x;
    if (i >= 3 * FD * FD) return;
    int l = i >> 14, r = i & (FD * FD - 1);
    int n = r >> 7, k = r & 127;
    const float* W = (l == 0) ? W0 : ((l == 1) ? W1 : W2);
    Wt[i] = f2bf(W[k * FD + n]);   // i = l*16384 + n*128 + k
}

// ---------------- degree histogram (int atomics, int4 edge loads) ----------------
__global__ void k_degrees(const int* __restrict__ src, const int* __restrict__ dst,
                          int* __restrict__ cnt_out, int* __restrict__ cnt_in) {
    const int total4 = NE / 4;
    for (int i = blockIdx.x * blockDim.x + threadIdx.x; i < total4;
         i += gridDim.x * blockDim.x) {
        int4 s = ((const int4*)src)[i];
        int4 d = ((const int4*)dst)[i];
        atomicAdd(&cnt_out[s.x], 1); atomicAdd(&cnt_out[s.y], 1);
        atomicAdd(&cnt_out[s.z], 1); atomicAdd(&cnt_out[s.w], 1);
        atomicAdd(&cnt_in[d.x], 1); atomicAdd(&cnt_in[d.y], 1);
        atomicAdd(&cnt_in[d.z], 1); atomicAdd(&cnt_in[d.w], 1);
    }
}

__global__ void k_invsqrt(const int* __restrict__ cnt, float* __restrict__ inv, int n) {
    int i = blockIdx.x * blockDim.x + threadIdx.x;
    if (i < n) inv[i] = rsqrtf((float)max(cnt[i], 1));
}

// ---------------- single-block scan, 4 elems/thread ----------------
__global__ __launch_bounds__(1024) void k_scan(const int* __restrict__ cnt_in,
                                               int* __restrict__ row_ptr,
                                               int* __restrict__ cursor) {
    __shared__ int wsum[16];
    __shared__ int wscan[16];
    __shared__ int carry_s;
    const int tid = threadIdx.x;
    const int lane = tid & 63;
    const int wid = tid >> 6;
    if (tid == 0) carry_s = 0;
    __syncthreads();
    for (int base = 0; base < NN; base += 4096) {
        const int i0 = base + tid * 4;
        int4 v = make_int4(0, 0, 0, 0);
        if (i0 + 3 < NN) {
            v = ((const int4*)(cnt_in + base))[tid];
        } else {
            if (i0 < NN) v.x = cnt_in[i0];
            if (i0 + 1 < NN) v.y = cnt_in[i0 + 1];
            if (i0 + 2 < NN) v.z = cnt_in[i0 + 2];
            if (i0 + 3 < NN) v.w = cnt_in[i0 + 3];
        }
        const int s = v.x + v.y + v.z + v.w;
        int incl = s;
        #pragma unroll
        for (int off = 1; off < 64; off <<= 1) {
            int t = __shfl_up(incl, off, 64);
            if (lane >= off) incl += t;
        }
        if (lane == 63) wsum[wid] = incl;
        __syncthreads();
        if (wid == 0) {
            int t = (lane < 16) ? wsum[lane] : 0;
            #pragma unroll
            for (int off = 1; off < 16; off <<= 1) {
                int u = __shfl_up(t, off, 64);
                if (lane >= off) t += u;
            }
            if (lane < 16) wscan[lane] = t;
        }
        __syncthreads();
        const int wbase = (wid > 0) ? wscan[wid - 1] : 0;
        int p = carry_s + wbase + incl - s;
        if (i0 < NN) { row_ptr[i0] = p; cursor[i0] = p; }
        if (i0 + 1 < NN) { row_ptr[i0 + 1] = p + v.x; cursor[i0 + 1] = p + v.x; }
        if (i0 + 2 < NN) { row_ptr[i0 + 2] = p + v.x + v.y; cursor[i0 + 2] = p + v.x + v.y; }
        if (i0 + 3 < NN) { row_ptr[i0 + 3] = p + v.x + v.y + v.z; cursor[i0 + 3] = p + v.x + v.y + v.z; }
        __syncthreads();
        if (tid == 0) carry_s += wscan[15];
        __syncthreads();
    }
    if (tid == 0) row_ptr[NN] = carry_s;
}

// ---------------- bucket cursors: bkt[b] = row_ptr[b<<9] ----------------
__global__ void k_bkt_init(const int* __restrict__ row_ptr, int* __restrict__ bkt) {
    int b = blockIdx.x * blockDim.x + threadIdx.x;
    if (b < NBKT) bkt[b] = row_ptr[min(b << 9, NN)];
}

// ---------------- P1: radix-partition edges into dst-buckets (pairs) ----------
__global__ __launch_bounds__(256) void k_part(const int* __restrict__ src,
                                              const int* __restrict__ dst,
                                              int* __restrict__ bkt_cursor,
                                              int2* __restrict__ pairs) {
    __shared__ int hist[NBKT];
    __shared__ int base[NBKT];
    __shared__ int lofs[NBKT];
    const int tid = threadIdx.x;
    const int e0 = blockIdx.x * PCH;
    for (int i = tid; i < NBKT; i += 256) { hist[i] = 0; lofs[i] = 0; }
    __syncthreads();
    int md[16], ms[16];
    #pragma unroll
    for (int k = 0; k < 16; ++k) {
        int e = e0 + k * 256 + tid;
        md[k] = (e < NE) ? dst[e] : -1;
        ms[k] = (e < NE) ? src[e] : 0;
    }
    #pragma unroll
    for (int k = 0; k < 16; ++k)
        if (md[k] >= 0) atomicAdd(&hist[md[k] >> 9], 1);
    __syncthreads();
    for (int i = tid; i < NBKT; i += 256)
        base[i] = hist[i] ? atomicAdd(&bkt_cursor[i], hist[i]) : 0;
    __syncthreads();
    #pragma unroll
    for (int k = 0; k < 16; ++k)
        if (md[k] >= 0) {
            int b = md[k] >> 9;
            int off = atomicAdd(&lofs[b], 1);
            pairs[base[b] + off] = make_int2(ms[k], md[k]);
        }
}

// ---------------- P2: CSR fill from bucket-sorted pairs ----------------
__global__ __launch_bounds__(256) void k_fill2(const int2* __restrict__ pairs,
                                               int* __restrict__ cursor,
                                               int* __restrict__ col, int nblk) {
    // bijective chunked swizzle (m204): consecutive logical chunks -> same XCD
    const int bid = blockIdx.x;
    const int q = nblk >> 3, r = nblk & 7;
    const int xcd = bid & 7, idx = bid >> 3;
    const int logical = (xcd < r ? xcd * (q + 1) : r * (q + 1) + (xcd - r) * q) + idx;
    const int e0 = logical * 1024;
    #pragma unroll
    for (int k = 0; k < 4; ++k) {
        int e = e0 + k * 256 + threadIdx.x;
        if (e < NE) {
            int2 p = pairs[e];
            int pos = atomicAdd(&cursor[p.y], 1);
            col[pos] = p.x;
        }
    }
}

// ---------------- MFMA GEMM: tmp[r][:] = fp16(inv_out[r] * (bf16(h[r][:]) @ bf16(W)))
__global__ __launch_bounds__(256) void k_gemm(const float* __restrict__ h, int hstride,
                                              const short* __restrict__ Wt,
                                              const float* __restrict__ inv_out,
                                              __half* __restrict__ tmp) {
    __shared__ short Ws[FD * LDA];   // Wt[n][k], padded rows: 34 KB
    __shared__ short hA[64 * LDA];   // h tile bf16, padded rows: 17 KB
    const int tid = threadIdx.x;
    for (int i = tid; i < FD * 16; i += 256) {   // 2048 chunks of 8 bf16
        int n = i >> 4, c = i & 15;
        short8 v = *(const short8*)(Wt + n * FD + c * 8);
        *(short8*)(&Ws[n * LDA + c * 8]) = v;
    }
    const int row0 = blockIdx.x * 128;
    const int wid = tid >> 6, lane = tid & 63;
    const int m = lane & 15, quad = lane >> 4;

    for (int sub = 0; sub < 2; ++sub) {
        const int rbase = row0 + sub * 64;
        __syncthreads();   // sub0: Ws staged; sub>0: prev compute done before hA overwrite
        for (int i = tid; i < 64 * 32; i += 256) {   // float4 chunks
            int r = i >> 5, c4 = i & 31;
            int gr = rbase + r;
            float4 v = make_float4(0.f, 0.f, 0.f, 0.f);
            if (gr < NN) v = ((const float4*)(h + (size_t)gr * hstride))[c4];
            short4 b;
            b.x = f2bf(v.x); b.y = f2bf(v.y); b.z = f2bf(v.z); b.w = f2bf(v.w);
            *(short4*)(&hA[r * LDA + c4 * 4]) = b;
        }
        __syncthreads();
        const int rtile = rbase + wid * 16;          // this wave's 16 rows
        short8 a0 = *(const short8*)(&hA[(wid * 16 + m) * LDA + 0 * 32 + quad * 8]);
        short8 a1 = *(const short8*)(&hA[(wid * 16 + m) * LDA + 1 * 32 + quad * 8]);
        short8 a2 = *(const short8*)(&hA[(wid * 16 + m) * LDA + 2 * 32 + quad * 8]);
        short8 a3 = *(const short8*)(&hA[(wid * 16 + m) * LDA + 3 * 32 + quad * 8]);
        float s0, s1, s2, s3;
        {
            int r = rtile + quad * 4;
            s0 = (r + 0 < NN) ? inv_out[r + 0] : 0.f;
            s1 = (r + 1 < NN) ? inv_out[r + 1] : 0.f;
            s2 = (r + 2 < NN) ? inv_out[r + 2] : 0.f;
            s3 = (r + 3 < NN) ? inv_out[r + 3] : 0.f;
        }
        #pragma unroll
        for (int ct = 0; ct < 8; ++ct) {
            f32x4 acc = {0.f, 0.f, 0.f, 0.f};
            short8 b0 = *(const short8*)(&Ws[(ct * 16 + m) * LDA + 0 * 32 + quad * 8]);
            short8 b1 = *(const short8*)(&Ws[(ct * 16 + m) * LDA + 1 * 32 + quad * 8]);
            short8 b2 = *(const short8*)(&Ws[(ct * 16 + m) * LDA + 2 * 32 + quad * 8]);
            short8 b3 = *(const short8*)(&Ws[(ct * 16 + m) * LDA + 3 * 32 + quad * 8]);
            acc = __builtin_amdgcn_mfma_f32_16x16x32_bf16(a0, b0, acc, 0, 0, 0);
            acc = __builtin_amdgcn_mfma_f32_16x16x32_bf16(a1, b1, acc, 0, 0, 0);
            acc = __builtin_amdgcn_mfma_f32_16x16x32_bf16(a2, b2, acc, 0, 0, 0);
            acc = __builtin_amdgcn_mfma_f32_16x16x32_bf16(a3, b3, acc, 0, 0, 0);
            const int r = rtile + quad * 4;
            const int c = ct * 16 + m;
            if (r + 3 < NN) {
                tmp[(size_t)(r + 0) * FD + c] = __float2half_rn(acc[0] * s0);
                tmp[(size_t)(r + 1) * FD + c] = __float2half_rn(acc[1] * s1);
                tmp[(size_t)(r + 2) * FD + c] = __float2half_rn(acc[2] * s2);
                tmp[(size_t)(r + 3) * FD + c] = __float2half_rn(acc[3] * s3);
            } else {
                if (r + 0 < NN) tmp[(size_t)(r + 0) * FD + c] = __float2half_rn(acc[0] * s0);
                if (r + 1 < NN) tmp[(size_t)(r + 1) * FD + c] = __float2half_rn(acc[1] * s1);
                if (r + 2 < NN) tmp[(size_t)(r + 2) * FD + c] = __float2half_rn(acc[2] * s2);
                if (r + 3 < NN) tmp[(size_t)(r + 3) * FD + c] = __float2half_rn(acc[3] * s3);
            }
        }
    }
}

// ---------------- gather: out[d][off:off+128] = relu(inv_in[d]*sum tmp[s] + b) ----
// One wave per node. 32-lane half-waves each own one edge: lane sl loads 8 B
// (4 halves) of the 256 B fp16 row; even/odd edges run on half 0/1 -> with a
// 4-deep unroll the wave keeps 8 edges in flight (vs 4 before; gather is
// latency-bound on L2/L3, not HBM-BW-bound). One shfl_xor(32) folds halves.
__global__ __launch_bounds__(256) void k_gather(const __half* __restrict__ tmp,
                                                const int* __restrict__ row_ptr,
                                                const int* __restrict__ col,
                                                const float* __restrict__ inv_in,
                                                const float* __restrict__ b,
                                                float* __restrict__ out, int off) {
    const int wid = threadIdx.x >> 6;
    const int lane = threadIdx.x & 63;
    const int half = lane >> 5;   // 0: even edges, 1: odd edges
    const int sl = lane & 31;     // position within the 256 B row (8 B per lane)
    const int node = blockIdx.x * 4 + wid;
    if (node >= NN) return;
    const int beg = row_ptr[node], end = row_ptr[node + 1];
    const h4v* t4 = (const h4v*)tmp;   // row = 32 h4v units
    float4 acc = make_float4(0.f, 0.f, 0.f, 0.f);
    int j = beg + half;
    for (; j + 6 < end; j += 8) {   // 4 edges per half per iter -> 8/wave in flight
        int s0 = col[j], s1 = col[j + 2], s2 = col[j + 4], s3 = col[j + 6];
        h4v v0 = t4[(size_t)s0 * 32 + sl];
        h4v v1 = t4[(size_t)s1 * 32 + sl];
        h4v v2 = t4[(size_t)s2 * 32 + sl];
        h4v v3 = t4[(size_t)s3 * 32 + sl];
        float2 l0 = __half22float2(v0.lo), h0 = __half22float2(v0.hi);
        float2 l1 = __half22float2(v1.lo), h1 = __half22float2(v1.hi);
        float2 l2 = __half22float2(v2.lo), h2 = __half22float2(v2.hi);
        float2 l3 = __half22float2(v3.lo), h3 = __half22float2(v3.hi);
        acc.x += (l0.x + l1.x) + (l2.x + l3.x);
        acc.y += (l0.y + l1.y) + (l2.y + l3.y);
        acc.z += (h0.x + h1.x) + (h2.x + h3.x);
        acc.w += (h0.y + h1.y) + (h2.y + h3.y);
    }
    for (; j < end; j += 2) {
        h4v v = t4[(size_t)col[j] * 32 + sl];
        float2 l = __half22float2(v.lo), h = __half22float2(v.hi);
        acc.x += l.x; acc.y += l.y; acc.z += h.x; acc.w += h.y;
    }
    // fold even/odd halves (identical column ranges)
    acc.x += __shfl_xor(acc.x, 32);
    acc.y += __shfl_xor(acc.y, 32);
    acc.z += __shfl_xor(acc.z, 32);
    acc.w += __shfl_xor(acc.w, 32);
    if (half == 0) {
        const float s = inv_in[node];
        const float4 bb = ((const float4*)b)[sl];
        float4 r;
        r.x = fmaxf(acc.x * s + bb.x, 0.f);
        r.y = fmaxf(acc.y * s + bb.y, 0.f);
        r.z = fmaxf(acc.z * s + bb.z, 0.f);
        r.w = fmaxf(acc.w * s + bb.w, 0.f);
        ((float4*)(out + (size_t)node * OS + off))[sl] = r;
    }
}

extern "C" void kernel_launch(void* const* d_in, const int* in_sizes, int n_in,
                              void* d_out, int out_size, void* d_ws, size_t ws_size,
                              hipStream_t stream) {
    const float* feat = (const float*)d_in[0];
    const float* W0 = (const float*)d_in[1];
    const float* b0 = (const float*)d_in[2];
    const float* W1 = (const float*)d_in[3];
    const float* b1 = (const float*)d_in[4];
    const float* W2 = (const float*)d_in[5];
    const float* b2 = (const float*)d_in[6];
    const int* src = (const int*)d_in[7];
    const int* dst = (const int*)d_in[8];
    float* out = (float*)d_out;
    float* ws = (float*)d_ws;

    __half* tmp = (__half*)ws;                // NN*FD halves = 25.6MB of the 51.2MB region
    int2* pairs = (int2*)(ws + (size_t)NN * 64);  // 12.8MB in the free upper half of tmp region
    int* cnt = (int*)(ws + (size_t)NN * FD);  // 2N ints (cnt_out | cnt_in)
    float* inv = (float*)(cnt + 2 * NN);      // 2N floats (inv_out | inv_in)
    int* row_ptr = (int*)(inv + 2 * NN);      // N+1 ints
    int* cursor = row_ptr + NN + 1;           // N ints
    int* col = cursor + NN;                   // NE ints
    short* Wt = (short*)(col + NE);           // 3*FD*FD bf16
    int* bkt = (int*)(Wt + 3 * FD * FD);      // NBKT ints

    hipMemsetAsync(cnt, 0, 2 * NN * sizeof(int), stream);
    k_init_out<<<4096, 256, 0, stream>>>(feat, out);
    k_prep_w<<<(3 * FD * FD + 255) / 256, 256, 0, stream>>>(W0, W1, W2, Wt);
    k_degrees<<<2048, 256, 0, stream>>>(src, dst, cnt, cnt + NN);
    k_invsqrt<<<(2 * NN + 255) / 256, 256, 0, stream>>>(cnt, inv, 2 * NN);
    k_scan<<<1, 1024, 0, stream>>>(cnt + NN, row_ptr, cursor);
    k_bkt_init<<<1, 256, 0, stream>>>(row_ptr, bkt);
    k_part<<<(NE + PCH - 1) / PCH, 256, 0, stream>>>(src, dst, bkt, pairs);
    {
        const int nblk = (NE + 1023) / 1024;
        k_fill2<<<nblk, 256, 0, stream>>>(pairs, cursor, col, nblk);
    }

    const float* bs[3] = {b0, b1, b2};
    const float* h = feat;
    int hstride = FD;
    for (int l = 0; l < 3; ++l) {
        k_gemm<<<(NN + 127) / 128, 256, 0, stream>>>(h, hstride, Wt + l * FD * FD, inv, tmp);
        k_gather<<<(NN + 3) / 4, 256, 0, stream>>>(tmp, row_ptr, col, inv + NN, bs[l], out,
                                                   FD * (l + 1));
        h = out + FD * (l + 1);
        hstride = OS;
    }
}